// Round 2
// baseline (5283.536 us; speedup 1.0000x reference)
//
#include <hip/hip_runtime.h>
#include <cstdint>

// ---------------------------------------------------------------------------
// SimpleViT forward on gfx950. bf16 MFMA for all GEMMs, f32 residual stream.
// B=32, T=196, D=768, NH=12, HD=64, L=12, MLP=3072, NC=1000.
// R2: split-K + f32-atomic epilogue for N=768 GEMMs (occupancy fix),
//     XCD co-location swizzle (bm padded to 56; same A-tile -> same XCD),
//     h pre-init kernel (posemb+bias), 4-row LayerNorm blocks.
// ---------------------------------------------------------------------------

typedef __bf16 bf16_t;
typedef __bf16 bf16x8 __attribute__((ext_vector_type(8)));
typedef float  f32x4  __attribute__((ext_vector_type(4)));

#define NLAYER 12
#define BMPAD 56   // 49 M-tiles padded to 56 (multiple of 8 -> XCD co-location)

// async global->LDS, 16B per lane (HW: wave-uniform base + lane*16)
__device__ __forceinline__ void g2lds16(const void* g, void* l) {
  __builtin_amdgcn_global_load_lds(
      (const __attribute__((address_space(1))) void*)g,
      (__attribute__((address_space(3))) void*)l, 16, 0, 0);
}

// ---------------------------------------------------------------------------
// Weight transpose + f32->bf16: in [R][C] f32 -> out [C][R] bf16 (batched).
// ---------------------------------------------------------------------------
__global__ __launch_bounds__(256) void tcvt(
    const float* __restrict__ in, bf16_t* __restrict__ out,
    int R, int C, long inStride, long outOuter, long outInner, int innerN)
{
  int bi = blockIdx.z;
  in  += (long)bi * inStride;
  out += (long)(bi / innerN) * outOuter + (long)(bi % innerN) * outInner;
  __shared__ float t[32][33];
  int c0 = blockIdx.x * 32, r0 = blockIdx.y * 32;
  int tx = threadIdx.x, ty = threadIdx.y;
  #pragma unroll
  for (int i = ty; i < 32; i += 8) {
    int r = r0 + i, c = c0 + tx;
    if (r < R && c < C) t[i][tx] = in[(long)r * C + c];
  }
  __syncthreads();
  #pragma unroll
  for (int i = ty; i < 32; i += 8) {
    int c = c0 + i, r = r0 + tx;
    if (r < R && c < C) out[(long)c * R + r] = (bf16_t)t[tx][i];
  }
}

// ---------------------------------------------------------------------------
// Patchify: x[32,3,224,224] f32 -> patches[6272,768] bf16
// ---------------------------------------------------------------------------
__global__ __launch_bounds__(256) void patchify(
    const float* __restrict__ x, bf16_t* __restrict__ patches)
{
  int idx = blockIdx.x * 256 + threadIdx.x;
  int bt = idx / 768, pd = idx % 768;
  int b = bt / 196, t = bt % 196;
  int gh = t / 14, gw = t % 14;
  int p1 = pd / 48, rem = pd % 48;
  int p2 = rem / 3, c = rem % 3;
  float v = x[(((long)(b * 3 + c) * 224) + gh * 16 + p1) * 224 + gw * 16 + p2];
  patches[idx] = (bf16_t)v;
}

// ---------------------------------------------------------------------------
// h init: h[b][t][d] = posemb(t,d) + embed_b[d]   (broadcast over b)
// grid 588, block 256
// ---------------------------------------------------------------------------
__global__ __launch_bounds__(256) void hinit(
    const float* __restrict__ eb, float* __restrict__ h)
{
  int idx = blockIdx.x * 256 + threadIdx.x;      // 0 .. 196*768-1
  int t = idx / 768, d = idx % 768;
  int gh = t / 14, gw = t % 14;
  int quadrant = d / 192, i = d % 192;
  float omega = powf(10000.0f, -(float)i / 191.0f);
  float arg = (quadrant < 2 ? (float)gw : (float)gh) * omega;
  float pv = ((quadrant & 1) == 0) ? sinf(arg) : cosf(arg);
  float v = pv + eb[d];
  #pragma unroll
  for (int b = 0; b < 32; ++b) h[(long)b * 150528 + idx] = v;
}

// ---------------------------------------------------------------------------
// LayerNorm: 4 rows per block (one wave each). h f32 -> xn bf16.
// ---------------------------------------------------------------------------
__global__ __launch_bounds__(256) void layernorm(
    const float* __restrict__ h, const float* __restrict__ g,
    const float* __restrict__ bb, bf16_t* __restrict__ xn)
{
  int row = blockIdx.x * 4 + (threadIdx.x >> 6);
  int lane = threadIdx.x & 63;
  const float4* hr = (const float4*)(h + (long)row * 768);
  float4 v[3];
  float s = 0.f, s2 = 0.f;
  #pragma unroll
  for (int i = 0; i < 3; ++i) {
    v[i] = hr[lane + 64 * i];
    s  += v[i].x + v[i].y + v[i].z + v[i].w;
    s2 += v[i].x * v[i].x + v[i].y * v[i].y + v[i].z * v[i].z + v[i].w * v[i].w;
  }
  #pragma unroll
  for (int d = 1; d < 64; d <<= 1) {
    s  += __shfl_xor(s, d, 64);
    s2 += __shfl_xor(s2, d, 64);
  }
  float mu = s * (1.0f / 768.0f);
  float var = s2 * (1.0f / 768.0f) - mu * mu;
  float rs = rsqrtf(var + 1e-5f);
  uint2* outv = (uint2*)(xn + (long)row * 768);
  const float4* gv = (const float4*)g;
  const float4* bv = (const float4*)bb;
  #pragma unroll
  for (int i = 0; i < 3; ++i) {
    int c4 = lane + 64 * i;
    float4 gg = gv[c4], b4 = bv[c4];
    union { bf16_t q[4]; uint2 u; } pk;
    pk.q[0] = (bf16_t)((v[i].x - mu) * rs * gg.x + b4.x);
    pk.q[1] = (bf16_t)((v[i].y - mu) * rs * gg.y + b4.y);
    pk.q[2] = (bf16_t)((v[i].z - mu) * rs * gg.z + b4.z);
    pk.q[3] = (bf16_t)((v[i].w - mu) * rs * gg.w + b4.w);
    outv[c4] = pk.u;
  }
}

// ---------------------------------------------------------------------------
// Main GEMM: C[M,N] = A[M,K] * Bt[N,K]^T.  128x128 tile, BK=32, 4 waves.
// 1-D grid, lin = (bn*KS + ks)*BMPAD + bm  -> same bm => same XCD (lin%8).
// EPI: 0 = bf16 store (QKV)
//      2 = unsafeAtomicAdd into f32 fout (+bias on ks==0)  [embed/Wo/MLP2]
//      3 = gelu(acc+bias) -> bf16  (MLP1)
//      4 = f32 plain store, masked (head)
// ---------------------------------------------------------------------------
template <int EPI>
__global__ __launch_bounds__(256) void gemm_bt(
    const bf16_t* __restrict__ A, const bf16_t* __restrict__ Bt,
    int Ktot, int KS, int ldc, int Mstore, int Nstore,
    const float* __restrict__ bias,
    float* __restrict__ fout, bf16_t* __restrict__ bout)
{
  int lin = blockIdx.x;
  int bm = lin % BMPAD;
  if (bm * 128 >= Mstore) return;          // padded bm tail: exit
  int rest = lin / BMPAD;
  int ks = rest % KS;
  int bn = rest / KS;
  int Ksl = Ktot / KS;
  int k0 = ks * Ksl;

  __shared__ __align__(16) bf16_t As[128 * 32];
  __shared__ __align__(16) bf16_t Bs[128 * 32];
  int tid = threadIdx.x;
  int wave = tid >> 6, lane = tid & 63, quad = lane >> 4, l16 = lane & 15;
  int wm = wave >> 1, wn = wave & 1;
  const bf16_t* Ab = A + (long)bm * 128 * Ktot;
  const bf16_t* Bb = Bt + (long)bn * 128 * Ktot;

  f32x4 zero = {0.f, 0.f, 0.f, 0.f};
  f32x4 acc[4][4];
  #pragma unroll
  for (int i = 0; i < 4; ++i)
    #pragma unroll
    for (int j = 0; j < 4; ++j) acc[i][j] = zero;

  int f0 = tid * 16;            // byte id in 4KB staging round
  int row0 = f0 >> 6;           // 0..63 (64B per 32-elem row)
  int ke0 = (f0 & 63) >> 1;     // element offset within row: 0,8,16,24

  for (int kt = k0; kt < k0 + Ksl; kt += 32) {
    __syncthreads();
    g2lds16(Ab + (long)row0 * Ktot + kt + ke0,        (char*)As + f0);
    g2lds16(Ab + (long)(row0 + 64) * Ktot + kt + ke0, (char*)As + f0 + 4096);
    g2lds16(Bb + (long)row0 * Ktot + kt + ke0,        (char*)Bs + f0);
    g2lds16(Bb + (long)(row0 + 64) * Ktot + kt + ke0, (char*)Bs + f0 + 4096);
    __syncthreads();

    bf16x8 af[4], bfr[4];
    #pragma unroll
    for (int i = 0; i < 4; ++i)
      af[i] = *(const bf16x8*)(As + (wm * 64 + i * 16 + l16) * 32 + quad * 8);
    #pragma unroll
    for (int j = 0; j < 4; ++j)
      bfr[j] = *(const bf16x8*)(Bs + (wn * 64 + j * 16 + l16) * 32 + quad * 8);
    #pragma unroll
    for (int i = 0; i < 4; ++i)
      #pragma unroll
      for (int j = 0; j < 4; ++j)
        acc[i][j] = __builtin_amdgcn_mfma_f32_16x16x32_bf16(af[i], bfr[j], acc[i][j], 0, 0, 0);
  }

  int m0 = bm * 128 + wm * 64, n0 = bn * 128 + wn * 64;
  #pragma unroll
  for (int i = 0; i < 4; ++i)
    #pragma unroll
    for (int j = 0; j < 4; ++j)
      #pragma unroll
      for (int r = 0; r < 4; ++r) {
        int row = m0 + i * 16 + quad * 4 + r;
        int col = n0 + j * 16 + l16;
        if (row >= Mstore || col >= Nstore) continue;
        float v = acc[i][j][r];
        if (EPI == 0) {
          bout[(long)row * ldc + col] = (bf16_t)v;
        } else if (EPI == 2) {
          float add = v + ((bias && ks == 0) ? bias[col] : 0.f);
          unsafeAtomicAdd(&fout[(long)row * ldc + col], add);
        } else if (EPI == 3) {
          float xg = v + bias[col];
          bout[(long)row * ldc + col] =
              (bf16_t)(0.5f * xg * (1.0f + erff(xg * 0.70710678118654752f)));
        } else {
          fout[(long)row * ldc + col] = v;
        }
      }
}

// ---------------------------------------------------------------------------
// V transpose: qkv v-part -> Vt[bh][64][224] bf16, cols s>=196 zero-filled.
// ---------------------------------------------------------------------------
__global__ __launch_bounds__(256) void vtrans(
    const bf16_t* __restrict__ qkv, bf16_t* __restrict__ Vt)
{
  int bh = blockIdx.z, b = bh / 12, h = bh % 12;
  __shared__ bf16_t t[32][33];
  int e0 = blockIdx.x * 32, s0 = blockIdx.y * 32;
  int tx = threadIdx.x, ty = threadIdx.y;
  #pragma unroll
  for (int i = ty; i < 32; i += 8) {
    int s = s0 + i;
    bf16_t v = (bf16_t)0.0f;
    if (s < 196) v = qkv[(long)(b * 196 + s) * 2304 + 1536 + h * 64 + e0 + tx];
    t[i][tx] = v;
  }
  __syncthreads();
  #pragma unroll
  for (int i = ty; i < 32; i += 8) {
    int e = e0 + i, s = s0 + tx;
    if (s < 224) Vt[(long)bh * 64 * 224 + (long)e * 224 + s] = t[tx][i];
  }
}

// ---------------------------------------------------------------------------
// Scores + softmax: one wave per (mtile, b, h).
// ---------------------------------------------------------------------------
__global__ __launch_bounds__(64) void attn_scores(
    const bf16_t* __restrict__ qkv, bf16_t* __restrict__ P)
{
  int mt = blockIdx.x, bh = blockIdx.y;
  int b = bh / 12, h = bh % 12;
  int lane = threadIdx.x, quad = lane >> 4, l16 = lane & 15;

  f32x4 zero = {0.f, 0.f, 0.f, 0.f};
  f32x4 acc[13];
  #pragma unroll
  for (int nt = 0; nt < 13; ++nt) acc[nt] = zero;

  long qoff = (long)(b * 196 + mt * 16 + l16) * 2304 + h * 64;
  #pragma unroll
  for (int kk = 0; kk < 2; ++kk) {
    bf16x8 a = *(const bf16x8*)(qkv + qoff + kk * 32 + quad * 8);
    #pragma unroll
    for (int nt = 0; nt < 13; ++nt) {
      long koff = (long)(b * 196 + nt * 16 + l16) * 2304 + 768 + h * 64 + kk * 32 + quad * 8;
      bf16x8 bb = *(const bf16x8*)(qkv + koff);
      acc[nt] = __builtin_amdgcn_mfma_f32_16x16x32_bf16(a, bb, acc[nt], 0, 0, 0);
    }
  }

  float p[13][4];
  #pragma unroll
  for (int nt = 0; nt < 13; ++nt)
    #pragma unroll
    for (int r = 0; r < 4; ++r) {
      float v = acc[nt][r] * 0.125f;
      if (nt == 12 && l16 >= 4) v = -1e30f;
      p[nt][r] = v;
    }

  #pragma unroll
  for (int r = 0; r < 4; ++r) {
    float mx = -1e30f;
    #pragma unroll
    for (int nt = 0; nt < 13; ++nt) mx = fmaxf(mx, p[nt][r]);
    #pragma unroll
    for (int d = 1; d < 16; d <<= 1) mx = fmaxf(mx, __shfl_xor(mx, d, 64));
    float sm = 0.f;
    #pragma unroll
    for (int nt = 0; nt < 13; ++nt) {
      float e = expf(p[nt][r] - mx);
      p[nt][r] = e;
      sm += e;
    }
    #pragma unroll
    for (int d = 1; d < 16; d <<= 1) sm += __shfl_xor(sm, d, 64);
    float inv = 1.0f / sm;
    #pragma unroll
    for (int nt = 0; nt < 13; ++nt) p[nt][r] *= inv;
  }

  long base = (long)bh * 208 * 224 + (long)(mt * 16 + quad * 4) * 224 + l16;
  #pragma unroll
  for (int nt = 0; nt < 13; ++nt)
    #pragma unroll
    for (int r = 0; r < 4; ++r)
      P[base + (long)r * 224 + nt * 16] = (bf16_t)p[nt][r];
}

// ---------------------------------------------------------------------------
// PV: att_tile[16,64] = P[16,224] @ V[224,64]
// ---------------------------------------------------------------------------
__global__ __launch_bounds__(64) void attn_pv(
    const bf16_t* __restrict__ P, const bf16_t* __restrict__ Vt,
    bf16_t* __restrict__ att)
{
  int mt = blockIdx.x, bh = blockIdx.y;
  int b = bh / 12, h = bh % 12;
  int lane = threadIdx.x, quad = lane >> 4, l16 = lane & 15;

  f32x4 zero = {0.f, 0.f, 0.f, 0.f};
  f32x4 acc[4];
  #pragma unroll
  for (int nt = 0; nt < 4; ++nt) acc[nt] = zero;

  const bf16_t* Prow = P + (long)bh * 208 * 224 + (long)(mt * 16 + l16) * 224;
  const bf16_t* Vb = Vt + (long)bh * 64 * 224;
  #pragma unroll
  for (int ks = 0; ks < 7; ++ks) {
    bf16x8 a = *(const bf16x8*)(Prow + ks * 32 + quad * 8);
    #pragma unroll
    for (int nt = 0; nt < 4; ++nt) {
      bf16x8 bb = *(const bf16x8*)(Vb + (long)(nt * 16 + l16) * 224 + ks * 32 + quad * 8);
      acc[nt] = __builtin_amdgcn_mfma_f32_16x16x32_bf16(a, bb, acc[nt], 0, 0, 0);
    }
  }

  #pragma unroll
  for (int nt = 0; nt < 4; ++nt)
    #pragma unroll
    for (int r = 0; r < 4; ++r) {
      int t = mt * 16 + quad * 4 + r;
      if (t < 196)
        att[(long)(b * 196 + t) * 768 + h * 64 + nt * 16 + l16] = (bf16_t)acc[nt][r];
    }
}

// ---------------------------------------------------------------------------
// Mean pool over tokens: h f32 [6272][768] -> hm bf16 [128][768] (rows 0..31)
// ---------------------------------------------------------------------------
__global__ __launch_bounds__(256) void meanpool(
    const float* __restrict__ h, bf16_t* __restrict__ hm)
{
  int d = blockIdx.y * 256 + threadIdx.x;
  int b = blockIdx.x;
  float s = 0.f;
  for (int t = 0; t < 196; ++t) s += h[(long)(b * 196 + t) * 768 + d];
  hm[b * 768 + d] = (bf16_t)(s * (1.0f / 196.0f));
}

// ---------------------------------------------------------------------------
// Host launch
// ---------------------------------------------------------------------------
extern "C" void kernel_launch(void* const* d_in, const int* in_sizes, int n_in,
                              void* d_out, int out_size, void* d_ws, size_t ws_size,
                              hipStream_t stream)
{
  const float* x       = (const float*)d_in[0];
  const float* embed_W = (const float*)d_in[1];
  const float* embed_b = (const float*)d_in[2];
  const float* Wq      = (const float*)d_in[3];
  const float* Wk      = (const float*)d_in[4];
  const float* Wv      = (const float*)d_in[5];
  const float* Wo      = (const float*)d_in[6];
  const float* bo      = (const float*)d_in[7];
  const float* ln1_g   = (const float*)d_in[8];
  const float* ln1_b   = (const float*)d_in[9];
  const float* ln2_g   = (const float*)d_in[10];
  const float* ln2_b   = (const float*)d_in[11];
  const float* W1      = (const float*)d_in[12];
  const float* b1      = (const float*)d_in[13];
  const float* W2      = (const float*)d_in[14];
  const float* b2      = (const float*)d_in[15];
  const float* head_W  = (const float*)d_in[16];

  // ---- workspace carve ----
  char* p = (char*)d_ws;
  auto carve = [&](size_t bytes) {
    char* r = p;
    p += (bytes + 255) & ~(size_t)255;
    return r;
  };
  bf16_t* embed_Wt = (bf16_t*)carve(589824ull * 2);           // [768][768]
  bf16_t* qkvT     = (bf16_t*)carve(21233664ull * 2);         // 12 x [2304][768]
  bf16_t* WoT      = (bf16_t*)carve(7077888ull * 2);          // 12 x [768][768]
  bf16_t* W1T      = (bf16_t*)carve(28311552ull * 2);         // 12 x [3072][768]
  bf16_t* W2T      = (bf16_t*)carve(28311552ull * 2);         // 12 x [768][3072]
  bf16_t* headWt   = (bf16_t*)carve(786432ull * 2);           // [1024][768] (rows>=1000 junk)
  bf16_t* patches  = (bf16_t*)carve(4816896ull * 2);          // [6272][768]
  float*  h        = (float*)carve(4816896ull * 4);           // [6272][768]
  bf16_t* xn       = (bf16_t*)carve(4816896ull * 2);          // [6272][768]
  bf16_t* qkv      = (bf16_t*)carve(14487552ull * 2);         // [6288][2304]
  bf16_t* Vt       = (bf16_t*)carve(5505024ull * 2);          // [384][64][224]
  bf16_t* Pb       = (bf16_t*)carve(38535168ull);             // union: P / hmlp
  bf16_t* att      = (bf16_t*)carve(4816896ull * 2);          // [6272][768]
  bf16_t* hm       = (bf16_t*)carve(98304ull * 2);            // [128][768]
  bf16_t* hmlp = Pb;
  (void)ws_size; (void)n_in; (void)in_sizes; (void)out_size;

  dim3 tb32(32, 8);

  // ---- weight prep: f32 -> bf16, B^T layout ----
  tcvt<<<dim3(24, 24, 1),   tb32, 0, stream>>>(embed_W, embed_Wt, 768, 768, 0, 0, 0, 1);
  tcvt<<<dim3(24, 24, 12),  tb32, 0, stream>>>(Wo, WoT, 768, 768, 589824, 589824, 0, 1);
  tcvt<<<dim3(2, 24, 144),  tb32, 0, stream>>>(Wq, qkvT,           768, 64, 49152, 1769472, 49152, 12);
  tcvt<<<dim3(2, 24, 144),  tb32, 0, stream>>>(Wk, qkvT + 589824,  768, 64, 49152, 1769472, 49152, 12);
  tcvt<<<dim3(2, 24, 144),  tb32, 0, stream>>>(Wv, qkvT + 1179648, 768, 64, 49152, 1769472, 49152, 12);
  tcvt<<<dim3(96, 24, 12),  tb32, 0, stream>>>(W1, W1T, 768, 3072, 2359296, 2359296, 0, 1);
  tcvt<<<dim3(24, 96, 12),  tb32, 0, stream>>>(W2, W2T, 3072, 768, 2359296, 2359296, 0, 1);
  tcvt<<<dim3(32, 24, 1),   tb32, 0, stream>>>(head_W, headWt, 768, 1000, 0, 0, 0, 1);

  // ---- patchify + h init (posemb + embed bias) ----
  patchify<<<18816, 256, 0, stream>>>(x, patches);
  hinit<<<588, 256, 0, stream>>>(embed_b, h);

  // ---- patch embed GEMM: h += patches @ embed_W  (split-K=2, atomic) ----
  gemm_bt<2><<<BMPAD * 6 * 2, 256, 0, stream>>>(
      patches, embed_Wt, 768, 2, 768, 6272, 768, nullptr, h, nullptr);

  for (int l = 0; l < NLAYER; ++l) {
    layernorm<<<1568, 256, 0, stream>>>(h, ln1_g + l * 768, ln1_b + l * 768, xn);
    gemm_bt<0><<<BMPAD * 18, 256, 0, stream>>>(
        xn, qkvT + (long)l * 1769472, 768, 1, 2304, 6272, 2304,
        nullptr, nullptr, qkv);
    vtrans<<<dim3(2, 7, 384), tb32, 0, stream>>>(qkv, Vt);
    attn_scores<<<dim3(13, 384), 64, 0, stream>>>(qkv, Pb);
    attn_pv<<<dim3(13, 384), 64, 0, stream>>>(Pb, Vt, att);
    gemm_bt<2><<<BMPAD * 6 * 4, 256, 0, stream>>>(
        att, WoT + (long)l * 589824, 768, 4, 768, 6272, 768,
        bo + l * 768, h, nullptr);
    layernorm<<<1568, 256, 0, stream>>>(h, ln2_g + l * 768, ln2_b + l * 768, xn);
    gemm_bt<3><<<BMPAD * 24, 256, 0, stream>>>(
        xn, W1T + (long)l * 2359296, 768, 1, 3072, 6272, 3072,
        b1 + l * 3072, nullptr, hmlp);
    gemm_bt<2><<<BMPAD * 6 * 4, 256, 0, stream>>>(
        hmlp, W2T + (long)l * 2359296, 3072, 4, 768, 6272, 768,
        b2 + l * 768, h, nullptr);
  }

  meanpool<<<dim3(32, 3), 256, 0, stream>>>(h, hm);
  gemm_bt<4><<<BMPAD * 8, 256, 0, stream>>>(
      hm, headWt, 768, 1, 1000, 32, 1000, nullptr, (float*)d_out, nullptr);
}

// Round 3
// 3833.222 us; speedup vs baseline: 1.3784x; 1.3784x over previous
//
#include <hip/hip_runtime.h>
#include <cstdint>

// ---------------------------------------------------------------------------
// SimpleViT forward on gfx950. bf16 MFMA GEMMs, f32 residual stream.
// R3: split-K=2 -> separate bf16 partial buffers (no atomics), reduction
//     fused into LayerNorm/meanpool; fused attention (P in LDS);
//     XCD swizzle kept (FETCH halving verified in R2).
// ---------------------------------------------------------------------------

typedef __bf16 bf16_t;
typedef __bf16 bf16x8 __attribute__((ext_vector_type(8)));
typedef __bf16 bf16x4 __attribute__((ext_vector_type(4)));
typedef float  f32x4  __attribute__((ext_vector_type(4)));

#define NLAYER 12
#define BMPAD 56           // M-tiles padded to mult of 8 -> XCD co-location
#define PSTRIDE 4816896l   // elements per partial buffer [6272][768]

__device__ __forceinline__ void g2lds16(const void* g, void* l) {
  __builtin_amdgcn_global_load_lds(
      (const __attribute__((address_space(1))) void*)g,
      (__attribute__((address_space(3))) void*)l, 16, 0, 0);
}

// ---------------------------------------------------------------------------
// Weight transpose + f32->bf16: in [R][C] f32 -> out [C][R] bf16 (batched).
// ---------------------------------------------------------------------------
__global__ __launch_bounds__(256) void tcvt(
    const float* __restrict__ in, bf16_t* __restrict__ out,
    int R, int C, long inStride, long outOuter, long outInner, int innerN)
{
  int bi = blockIdx.z;
  in  += (long)bi * inStride;
  out += (long)(bi / innerN) * outOuter + (long)(bi % innerN) * outInner;
  __shared__ float t[32][33];
  int c0 = blockIdx.x * 32, r0 = blockIdx.y * 32;
  int tx = threadIdx.x, ty = threadIdx.y;
  #pragma unroll
  for (int i = ty; i < 32; i += 8) {
    int r = r0 + i, c = c0 + tx;
    if (r < R && c < C) t[i][tx] = in[(long)r * C + c];
  }
  __syncthreads();
  #pragma unroll
  for (int i = ty; i < 32; i += 8) {
    int c = c0 + i, r = r0 + tx;
    if (r < R && c < C) out[(long)c * R + r] = (bf16_t)t[tx][i];
  }
}

// ---------------------------------------------------------------------------
// Patchify: x[32,3,224,224] f32 -> patches[6272,768] bf16
// ---------------------------------------------------------------------------
__global__ __launch_bounds__(256) void patchify(
    const float* __restrict__ x, bf16_t* __restrict__ patches)
{
  int idx = blockIdx.x * 256 + threadIdx.x;
  int bt = idx / 768, pd = idx % 768;
  int b = bt / 196, t = bt % 196;
  int gh = t / 14, gw = t % 14;
  int p1 = pd / 48, rem = pd % 48;
  int p2 = rem / 3, c = rem % 3;
  float v = x[(((long)(b * 3 + c) * 224) + gh * 16 + p1) * 224 + gw * 16 + p2];
  patches[idx] = (bf16_t)v;
}

// ---------------------------------------------------------------------------
// h init: h[b][t][d] = posemb(t,d) + embed_b[d]
// ---------------------------------------------------------------------------
__global__ __launch_bounds__(256) void hinit(
    const float* __restrict__ eb, float* __restrict__ h)
{
  int idx = blockIdx.x * 256 + threadIdx.x;      // 0 .. 196*768-1
  int t = idx / 768, d = idx % 768;
  int gh = t / 14, gw = t % 14;
  int quadrant = d / 192, i = d % 192;
  float omega = powf(10000.0f, -(float)i / 191.0f);
  float arg = (quadrant < 2 ? (float)gw : (float)gh) * omega;
  float pv = ((quadrant & 1) == 0) ? sinf(arg) : cosf(arg);
  float v = pv + eb[d];
  #pragma unroll
  for (int b = 0; b < 32; ++b) h[(long)b * 150528 + idx] = v;
}

// ---------------------------------------------------------------------------
// Fused residual + LayerNorm: h += p0 + p1 + bias; xn = LN(h)*g+b.
// 4 rows per block (one wave each).
// ---------------------------------------------------------------------------
__global__ __launch_bounds__(256) void ln_fuse(
    float* __restrict__ h, const bf16_t* __restrict__ pbuf,
    const float* __restrict__ bias, const float* __restrict__ g,
    const float* __restrict__ bb, bf16_t* __restrict__ xn)
{
  int row = blockIdx.x * 4 + (threadIdx.x >> 6);
  int lane = threadIdx.x & 63;
  float* hr = h + (long)row * 768;
  const bf16_t* p0 = pbuf + (long)row * 768;
  const bf16_t* p1 = p0 + PSTRIDE;
  float4 v[3];
  float s = 0.f, s2 = 0.f;
  #pragma unroll
  for (int i = 0; i < 3; ++i) {
    int c4 = lane + 64 * i;
    float4 hv = ((const float4*)hr)[c4];
    bf16x4 q0 = *(const bf16x4*)(p0 + c4 * 4);
    bf16x4 q1 = *(const bf16x4*)(p1 + c4 * 4);
    float4 bv = {0.f, 0.f, 0.f, 0.f};
    if (bias) bv = ((const float4*)bias)[c4];
    hv.x += (float)q0[0] + (float)q1[0] + bv.x;
    hv.y += (float)q0[1] + (float)q1[1] + bv.y;
    hv.z += (float)q0[2] + (float)q1[2] + bv.z;
    hv.w += (float)q0[3] + (float)q1[3] + bv.w;
    ((float4*)hr)[c4] = hv;
    v[i] = hv;
    s  += hv.x + hv.y + hv.z + hv.w;
    s2 += hv.x * hv.x + hv.y * hv.y + hv.z * hv.z + hv.w * hv.w;
  }
  #pragma unroll
  for (int d = 1; d < 64; d <<= 1) {
    s  += __shfl_xor(s, d, 64);
    s2 += __shfl_xor(s2, d, 64);
  }
  float mu = s * (1.0f / 768.0f);
  float var = s2 * (1.0f / 768.0f) - mu * mu;
  float rs = rsqrtf(var + 1e-5f);
  uint2* outv = (uint2*)(xn + (long)row * 768);
  const float4* gv = (const float4*)g;
  const float4* bv2 = (const float4*)bb;
  #pragma unroll
  for (int i = 0; i < 3; ++i) {
    int c4 = lane + 64 * i;
    float4 gg = gv[c4], b4 = bv2[c4];
    union { bf16_t q[4]; uint2 u; } pk;
    pk.q[0] = (bf16_t)((v[i].x - mu) * rs * gg.x + b4.x);
    pk.q[1] = (bf16_t)((v[i].y - mu) * rs * gg.y + b4.y);
    pk.q[2] = (bf16_t)((v[i].z - mu) * rs * gg.z + b4.z);
    pk.q[3] = (bf16_t)((v[i].w - mu) * rs * gg.w + b4.w);
    outv[c4] = pk.u;
  }
}

// ---------------------------------------------------------------------------
// Main GEMM: C[M,N] = A[M,K] * Bt[N,K]^T.  128x128 tile, BK=32, 4 waves.
// 1-D grid, lin = (bn*KS + ks)*BMPAD + bm  -> same bm => same XCD (lin%8).
// EPI: 0 = bf16 store (QKV)
//      3 = gelu(acc+bias) -> bf16  (MLP1)
//      4 = f32 plain store, masked (head)
//      5 = bf16 partial store at bout + ks*PSTRIDE  (embed/Wo/MLP2)
// ---------------------------------------------------------------------------
template <int EPI>
__global__ __launch_bounds__(256) void gemm_bt(
    const bf16_t* __restrict__ A, const bf16_t* __restrict__ Bt,
    int Ktot, int KS, int ldc, int Mstore, int Nstore,
    const float* __restrict__ bias,
    float* __restrict__ fout, bf16_t* __restrict__ bout)
{
  int lin = blockIdx.x;
  int bm = lin % BMPAD;
  if (bm * 128 >= Mstore) return;
  int rest = lin / BMPAD;
  int ks = rest % KS;
  int bn = rest / KS;
  int Ksl = Ktot / KS;
  int k0 = ks * Ksl;

  __shared__ __align__(16) bf16_t As[128 * 32];
  __shared__ __align__(16) bf16_t Bs[128 * 32];
  int tid = threadIdx.x;
  int wave = tid >> 6, lane = tid & 63, quad = lane >> 4, l16 = lane & 15;
  int wm = wave >> 1, wn = wave & 1;
  const bf16_t* Ab = A + (long)bm * 128 * Ktot;
  const bf16_t* Bb = Bt + (long)bn * 128 * Ktot;

  f32x4 zero = {0.f, 0.f, 0.f, 0.f};
  f32x4 acc[4][4];
  #pragma unroll
  for (int i = 0; i < 4; ++i)
    #pragma unroll
    for (int j = 0; j < 4; ++j) acc[i][j] = zero;

  int f0 = tid * 16;
  int row0 = f0 >> 6;
  int ke0 = (f0 & 63) >> 1;

  for (int kt = k0; kt < k0 + Ksl; kt += 32) {
    __syncthreads();
    g2lds16(Ab + (long)row0 * Ktot + kt + ke0,        (char*)As + f0);
    g2lds16(Ab + (long)(row0 + 64) * Ktot + kt + ke0, (char*)As + f0 + 4096);
    g2lds16(Bb + (long)row0 * Ktot + kt + ke0,        (char*)Bs + f0);
    g2lds16(Bb + (long)(row0 + 64) * Ktot + kt + ke0, (char*)Bs + f0 + 4096);
    __syncthreads();

    bf16x8 af[4], bfr[4];
    #pragma unroll
    for (int i = 0; i < 4; ++i)
      af[i] = *(const bf16x8*)(As + (wm * 64 + i * 16 + l16) * 32 + quad * 8);
    #pragma unroll
    for (int j = 0; j < 4; ++j)
      bfr[j] = *(const bf16x8*)(Bs + (wn * 64 + j * 16 + l16) * 32 + quad * 8);
    #pragma unroll
    for (int i = 0; i < 4; ++i)
      #pragma unroll
      for (int j = 0; j < 4; ++j)
        acc[i][j] = __builtin_amdgcn_mfma_f32_16x16x32_bf16(af[i], bfr[j], acc[i][j], 0, 0, 0);
  }

  int m0 = bm * 128 + wm * 64, n0 = bn * 128 + wn * 64;
  #pragma unroll
  for (int i = 0; i < 4; ++i)
    #pragma unroll
    for (int j = 0; j < 4; ++j)
      #pragma unroll
      for (int r = 0; r < 4; ++r) {
        int row = m0 + i * 16 + quad * 4 + r;
        int col = n0 + j * 16 + l16;
        if (row >= Mstore || col >= Nstore) continue;
        float v = acc[i][j][r];
        if (EPI == 0) {
          bout[(long)row * ldc + col] = (bf16_t)v;
        } else if (EPI == 3) {
          float xg = v + bias[col];
          bout[(long)row * ldc + col] =
              (bf16_t)(0.5f * xg * (1.0f + erff(xg * 0.70710678118654752f)));
        } else if (EPI == 4) {
          fout[(long)row * ldc + col] = v;
        } else {  // EPI 5: bf16 partial
          bout[(long)ks * PSTRIDE + (long)row * ldc + col] = (bf16_t)v;
        }
      }
}

// ---------------------------------------------------------------------------
// V transpose: qkv v-part -> Vt[bh][64][224] bf16, cols s>=196 zero-filled.
// ---------------------------------------------------------------------------
__global__ __launch_bounds__(256) void vtrans(
    const bf16_t* __restrict__ qkv, bf16_t* __restrict__ Vt)
{
  int bh = blockIdx.z, b = bh / 12, h = bh % 12;
  __shared__ bf16_t t[32][33];
  int e0 = blockIdx.x * 32, s0 = blockIdx.y * 32;
  int tx = threadIdx.x, ty = threadIdx.y;
  #pragma unroll
  for (int i = ty; i < 32; i += 8) {
    int s = s0 + i;
    bf16_t v = (bf16_t)0.0f;
    if (s < 196) v = qkv[(long)(b * 196 + s) * 2304 + 1536 + h * 64 + e0 + tx];
    t[i][tx] = v;
  }
  __syncthreads();
  #pragma unroll
  for (int i = ty; i < 32; i += 8) {
    int e = e0 + i, s = s0 + tx;
    if (s < 224) Vt[(long)bh * 64 * 224 + (long)e * 224 + s] = t[tx][i];
  }
}

// ---------------------------------------------------------------------------
// Fused attention: scores (Q@K^T) -> softmax -> P in LDS -> P@V -> att.
// One wave per (mt, bh). P LDS rows padded to 232 elems (2-way-free banks).
// ---------------------------------------------------------------------------
__global__ __launch_bounds__(64) void attn_fused(
    const bf16_t* __restrict__ qkv, const bf16_t* __restrict__ Vt,
    bf16_t* __restrict__ att)
{
  __shared__ __align__(16) bf16_t Pl[16 * 232];
  int mt = blockIdx.x, bh = blockIdx.y;
  int b = bh / 12, h = bh % 12;
  int lane = threadIdx.x, quad = lane >> 4, l16 = lane & 15;

  // zero the pad region cols 208..223 (read by PV k-step 6, quads 2-3)
  #pragma unroll
  for (int i = 0; i < 4; ++i) {
    int idx = lane + 64 * i;              // 0..255
    Pl[(idx >> 4) * 232 + 208 + (idx & 15)] = (bf16_t)0.0f;
  }

  // ---- scores: S[16,208] = Q_tile @ K^T ----
  f32x4 zero = {0.f, 0.f, 0.f, 0.f};
  f32x4 acc[13];
  #pragma unroll
  for (int nt = 0; nt < 13; ++nt) acc[nt] = zero;

  long qoff = (long)(b * 196 + mt * 16 + l16) * 2304 + h * 64;
  #pragma unroll
  for (int kk = 0; kk < 2; ++kk) {
    bf16x8 a = *(const bf16x8*)(qkv + qoff + kk * 32 + quad * 8);
    #pragma unroll
    for (int nt = 0; nt < 13; ++nt) {
      long koff = (long)(b * 196 + nt * 16 + l16) * 2304 + 768 + h * 64 + kk * 32 + quad * 8;
      bf16x8 bb = *(const bf16x8*)(qkv + koff);
      acc[nt] = __builtin_amdgcn_mfma_f32_16x16x32_bf16(a, bb, acc[nt], 0, 0, 0);
    }
  }

  float p[13][4];
  #pragma unroll
  for (int nt = 0; nt < 13; ++nt)
    #pragma unroll
    for (int r = 0; r < 4; ++r) {
      float v = acc[nt][r] * 0.125f;
      if (nt == 12 && l16 >= 4) v = -1e30f;
      p[nt][r] = v;
    }

  #pragma unroll
  for (int r = 0; r < 4; ++r) {
    float mx = -1e30f;
    #pragma unroll
    for (int nt = 0; nt < 13; ++nt) mx = fmaxf(mx, p[nt][r]);
    #pragma unroll
    for (int d = 1; d < 16; d <<= 1) mx = fmaxf(mx, __shfl_xor(mx, d, 64));
    float sm = 0.f;
    #pragma unroll
    for (int nt = 0; nt < 13; ++nt) {
      float e = expf(p[nt][r] - mx);
      p[nt][r] = e;
      sm += e;
    }
    #pragma unroll
    for (int d = 1; d < 16; d <<= 1) sm += __shfl_xor(sm, d, 64);
    float inv = 1.0f / sm;
    #pragma unroll
    for (int nt = 0; nt < 13; ++nt) p[nt][r] *= inv;
  }

  // ---- P -> LDS (C-layout: row=quad*4+r, col=nt*16+l16) ----
  #pragma unroll
  for (int nt = 0; nt < 13; ++nt)
    #pragma unroll
    for (int r = 0; r < 4; ++r)
      Pl[(quad * 4 + r) * 232 + nt * 16 + l16] = (bf16_t)p[nt][r];
  __syncthreads();

  // ---- PV: att_tile[16,64] = P[16,224] @ V[224,64] ----
  f32x4 pv[4];
  #pragma unroll
  for (int nt = 0; nt < 4; ++nt) pv[nt] = zero;
  const bf16_t* Vb = Vt + (long)bh * 64 * 224;
  #pragma unroll
  for (int ks = 0; ks < 7; ++ks) {
    bf16x8 a = *(const bf16x8*)(Pl + l16 * 232 + ks * 32 + quad * 8);
    #pragma unroll
    for (int nt = 0; nt < 4; ++nt) {
      bf16x8 bb = *(const bf16x8*)(Vb + (long)(nt * 16 + l16) * 224 + ks * 32 + quad * 8);
      pv[nt] = __builtin_amdgcn_mfma_f32_16x16x32_bf16(a, bb, pv[nt], 0, 0, 0);
    }
  }

  #pragma unroll
  for (int nt = 0; nt < 4; ++nt)
    #pragma unroll
    for (int r = 0; r < 4; ++r) {
      int t = mt * 16 + quad * 4 + r;
      if (t < 196)
        att[(long)(b * 196 + t) * 768 + h * 64 + nt * 16 + l16] = (bf16_t)pv[nt][r];
    }
}

// ---------------------------------------------------------------------------
// Mean pool + final MLP2 partial reduction: hm[b][d] = mean_t(h+p0+p1) + bias
// ---------------------------------------------------------------------------
__global__ __launch_bounds__(256) void meanpool_fuse(
    const float* __restrict__ h, const bf16_t* __restrict__ pbuf,
    const float* __restrict__ bias, bf16_t* __restrict__ hm)
{
  int d = blockIdx.y * 256 + threadIdx.x;
  int b = blockIdx.x;
  float s = 0.f;
  for (int t = 0; t < 196; ++t) {
    long idx = (long)(b * 196 + t) * 768 + d;
    s += h[idx] + (float)pbuf[idx] + (float)pbuf[idx + PSTRIDE];
  }
  hm[b * 768 + d] = (bf16_t)(s * (1.0f / 196.0f) + bias[d]);
}

// ---------------------------------------------------------------------------
// Host launch
// ---------------------------------------------------------------------------
extern "C" void kernel_launch(void* const* d_in, const int* in_sizes, int n_in,
                              void* d_out, int out_size, void* d_ws, size_t ws_size,
                              hipStream_t stream)
{
  const float* x       = (const float*)d_in[0];
  const float* embed_W = (const float*)d_in[1];
  const float* embed_b = (const float*)d_in[2];
  const float* Wq      = (const float*)d_in[3];
  const float* Wk      = (const float*)d_in[4];
  const float* Wv      = (const float*)d_in[5];
  const float* Wo      = (const float*)d_in[6];
  const float* bo      = (const float*)d_in[7];
  const float* ln1_g   = (const float*)d_in[8];
  const float* ln1_b   = (const float*)d_in[9];
  const float* ln2_g   = (const float*)d_in[10];
  const float* ln2_b   = (const float*)d_in[11];
  const float* W1      = (const float*)d_in[12];
  const float* b1      = (const float*)d_in[13];
  const float* W2      = (const float*)d_in[14];
  const float* b2      = (const float*)d_in[15];
  const float* head_W  = (const float*)d_in[16];

  char* p = (char*)d_ws;
  auto carve = [&](size_t bytes) {
    char* r = p;
    p += (bytes + 255) & ~(size_t)255;
    return r;
  };
  bf16_t* embed_Wt = (bf16_t*)carve(589824ull * 2);
  bf16_t* qkvT     = (bf16_t*)carve(21233664ull * 2);
  bf16_t* WoT      = (bf16_t*)carve(7077888ull * 2);
  bf16_t* W1T      = (bf16_t*)carve(28311552ull * 2);
  bf16_t* W2T      = (bf16_t*)carve(28311552ull * 2);
  bf16_t* headWt   = (bf16_t*)carve(786432ull * 2);
  bf16_t* patches  = (bf16_t*)carve(4816896ull * 2);
  float*  h        = (float*)carve(4816896ull * 4);
  bf16_t* xn       = (bf16_t*)carve(4816896ull * 2);
  bf16_t* qkv      = (bf16_t*)carve(14487552ull * 2);
  bf16_t* Vt       = (bf16_t*)carve(5505024ull * 2);
  bf16_t* hmlp     = (bf16_t*)carve(19267584ull * 2);
  bf16_t* att      = (bf16_t*)carve(4816896ull * 2);
  bf16_t* pbuf     = (bf16_t*)carve(2ull * PSTRIDE * 2);   // 2 partial bufs
  bf16_t* hm       = (bf16_t*)carve(98304ull * 2);
  (void)ws_size; (void)n_in; (void)in_sizes; (void)out_size;

  dim3 tb32(32, 8);

  // ---- weight prep ----
  tcvt<<<dim3(24, 24, 1),   tb32, 0, stream>>>(embed_W, embed_Wt, 768, 768, 0, 0, 0, 1);
  tcvt<<<dim3(24, 24, 12),  tb32, 0, stream>>>(Wo, WoT, 768, 768, 589824, 589824, 0, 1);
  tcvt<<<dim3(2, 24, 144),  tb32, 0, stream>>>(Wq, qkvT,           768, 64, 49152, 1769472, 49152, 12);
  tcvt<<<dim3(2, 24, 144),  tb32, 0, stream>>>(Wk, qkvT + 589824,  768, 64, 49152, 1769472, 49152, 12);
  tcvt<<<dim3(2, 24, 144),  tb32, 0, stream>>>(Wv, qkvT + 1179648, 768, 64, 49152, 1769472, 49152, 12);
  tcvt<<<dim3(96, 24, 12),  tb32, 0, stream>>>(W1, W1T, 768, 3072, 2359296, 2359296, 0, 1);
  tcvt<<<dim3(24, 96, 12),  tb32, 0, stream>>>(W2, W2T, 3072, 768, 2359296, 2359296, 0, 1);
  tcvt<<<dim3(32, 24, 1),   tb32, 0, stream>>>(head_W, headWt, 768, 1000, 0, 0, 0, 1);

  patchify<<<18816, 256, 0, stream>>>(x, patches);
  hinit<<<588, 256, 0, stream>>>(embed_b, h);

  // embed partials (split-K=2)
  gemm_bt<5><<<BMPAD * 6 * 2, 256, 0, stream>>>(
      patches, embed_Wt, 768, 2, 768, 6272, 768, nullptr, nullptr, pbuf);

  for (int l = 0; l < NLAYER; ++l) {
    // h += partials (+ bias of producer); xn = LN1(h)
    ln_fuse<<<1568, 256, 0, stream>>>(
        h, pbuf, l == 0 ? nullptr : b2 + (l - 1) * 768,
        ln1_g + l * 768, ln1_b + l * 768, xn);
    gemm_bt<0><<<BMPAD * 18, 256, 0, stream>>>(
        xn, qkvT + (long)l * 1769472, 768, 1, 2304, 6272, 2304,
        nullptr, nullptr, qkv);
    vtrans<<<dim3(2, 7, 384), tb32, 0, stream>>>(qkv, Vt);
    attn_fused<<<dim3(13, 384), 64, 0, stream>>>(qkv, Vt, att);
    gemm_bt<5><<<BMPAD * 6 * 2, 256, 0, stream>>>(
        att, WoT + (long)l * 589824, 768, 2, 768, 6272, 768,
        nullptr, nullptr, pbuf);
    ln_fuse<<<1568, 256, 0, stream>>>(
        h, pbuf, bo + l * 768, ln2_g + l * 768, ln2_b + l * 768, xn);
    gemm_bt<3><<<BMPAD * 24, 256, 0, stream>>>(
        xn, W1T + (long)l * 2359296, 768, 1, 3072, 6272, 3072,
        b1 + l * 3072, nullptr, hmlp);
    gemm_bt<5><<<BMPAD * 6 * 2, 256, 0, stream>>>(
        hmlp, W2T + (long)l * 2359296, 3072, 2, 768, 6272, 768,
        nullptr, nullptr, pbuf);
  }

  meanpool_fuse<<<dim3(32, 3), 256, 0, stream>>>(h, pbuf, b2 + 11 * 768, hm);
  gemm_bt<4><<<BMPAD * 8, 256, 0, stream>>>(
      hm, headWt, 768, 1, 1000, 32, 1000, nullptr, (float*)d_out, nullptr);
}

// Round 4
// 3555.698 us; speedup vs baseline: 1.4859x; 1.0781x over previous
//
#include <hip/hip_runtime.h>
#include <cstdint>

// ---------------------------------------------------------------------------
// SimpleViT forward on gfx950. bf16 MFMA GEMMs, f32 residual stream.
// R4: gemm_bt compile-time K/KS + __launch_bounds__(256,4) (target 128 unified
//     regs -> 4 blocks/CU); GELU erf->tanh via __expf (epilogue VALU cut);
//     MLP2 split-K=4. Split-K partials + swizzle from R3 kept.
// ---------------------------------------------------------------------------

typedef __bf16 bf16_t;
typedef __bf16 bf16x8 __attribute__((ext_vector_type(8)));
typedef __bf16 bf16x4 __attribute__((ext_vector_type(4)));
typedef float  f32x4  __attribute__((ext_vector_type(4)));

#define NLAYER 12
#define BMPAD 56           // M-tiles padded to mult of 8 -> XCD co-location
#define PSTRIDE 4816896l   // elements per partial buffer [6272][768]

__device__ __forceinline__ void g2lds16(const void* g, void* l) {
  __builtin_amdgcn_global_load_lds(
      (const __attribute__((address_space(1))) void*)g,
      (__attribute__((address_space(3))) void*)l, 16, 0, 0);
}

// ---------------------------------------------------------------------------
// Weight transpose + f32->bf16: in [R][C] f32 -> out [C][R] bf16 (batched).
// ---------------------------------------------------------------------------
__global__ __launch_bounds__(256) void tcvt(
    const float* __restrict__ in, bf16_t* __restrict__ out,
    int R, int C, long inStride, long outOuter, long outInner, int innerN)
{
  int bi = blockIdx.z;
  in  += (long)bi * inStride;
  out += (long)(bi / innerN) * outOuter + (long)(bi % innerN) * outInner;
  __shared__ float t[32][33];
  int c0 = blockIdx.x * 32, r0 = blockIdx.y * 32;
  int tx = threadIdx.x, ty = threadIdx.y;
  #pragma unroll
  for (int i = ty; i < 32; i += 8) {
    int r = r0 + i, c = c0 + tx;
    if (r < R && c < C) t[i][tx] = in[(long)r * C + c];
  }
  __syncthreads();
  #pragma unroll
  for (int i = ty; i < 32; i += 8) {
    int c = c0 + i, r = r0 + tx;
    if (r < R && c < C) out[(long)c * R + r] = (bf16_t)t[tx][i];
  }
}

// ---------------------------------------------------------------------------
// Patchify: x[32,3,224,224] f32 -> patches[6272,768] bf16
// ---------------------------------------------------------------------------
__global__ __launch_bounds__(256) void patchify(
    const float* __restrict__ x, bf16_t* __restrict__ patches)
{
  int idx = blockIdx.x * 256 + threadIdx.x;
  int bt = idx / 768, pd = idx % 768;
  int b = bt / 196, t = bt % 196;
  int gh = t / 14, gw = t % 14;
  int p1 = pd / 48, rem = pd % 48;
  int p2 = rem / 3, c = rem % 3;
  float v = x[(((long)(b * 3 + c) * 224) + gh * 16 + p1) * 224 + gw * 16 + p2];
  patches[idx] = (bf16_t)v;
}

// ---------------------------------------------------------------------------
// h init: h[b][t][d] = posemb(t,d) + embed_b[d]
// ---------------------------------------------------------------------------
__global__ __launch_bounds__(256) void hinit(
    const float* __restrict__ eb, float* __restrict__ h)
{
  int idx = blockIdx.x * 256 + threadIdx.x;      // 0 .. 196*768-1
  int t = idx / 768, d = idx % 768;
  int gh = t / 14, gw = t % 14;
  int quadrant = d / 192, i = d % 192;
  float omega = powf(10000.0f, -(float)i / 191.0f);
  float arg = (quadrant < 2 ? (float)gw : (float)gh) * omega;
  float pv = ((quadrant & 1) == 0) ? sinf(arg) : cosf(arg);
  float v = pv + eb[d];
  #pragma unroll
  for (int b = 0; b < 32; ++b) h[(long)b * 150528 + idx] = v;
}

// ---------------------------------------------------------------------------
// Fused residual + LayerNorm: h += sum(partials) + bias; xn = LN(h)*g+b.
// 4 rows per block (one wave each). nparts in {2,4}.
// ---------------------------------------------------------------------------
__global__ __launch_bounds__(256) void ln_fuse(
    float* __restrict__ h, const bf16_t* __restrict__ pbuf, int nparts,
    const float* __restrict__ bias, const float* __restrict__ g,
    const float* __restrict__ bb, bf16_t* __restrict__ xn)
{
  int row = blockIdx.x * 4 + (threadIdx.x >> 6);
  int lane = threadIdx.x & 63;
  float* hr = h + (long)row * 768;
  const bf16_t* pr = pbuf + (long)row * 768;
  float4 v[3];
  float s = 0.f, s2 = 0.f;
  #pragma unroll
  for (int i = 0; i < 3; ++i) {
    int c4 = lane + 64 * i;
    float4 hv = ((const float4*)hr)[c4];
    float4 acc = {0.f, 0.f, 0.f, 0.f};
    for (int pp = 0; pp < nparts; ++pp) {
      bf16x4 q = *(const bf16x4*)(pr + (long)pp * PSTRIDE + c4 * 4);
      acc.x += (float)q[0]; acc.y += (float)q[1];
      acc.z += (float)q[2]; acc.w += (float)q[3];
    }
    if (bias) {
      float4 bv = ((const float4*)bias)[c4];
      acc.x += bv.x; acc.y += bv.y; acc.z += bv.z; acc.w += bv.w;
    }
    hv.x += acc.x; hv.y += acc.y; hv.z += acc.z; hv.w += acc.w;
    ((float4*)hr)[c4] = hv;
    v[i] = hv;
    s  += hv.x + hv.y + hv.z + hv.w;
    s2 += hv.x * hv.x + hv.y * hv.y + hv.z * hv.z + hv.w * hv.w;
  }
  #pragma unroll
  for (int d = 1; d < 64; d <<= 1) {
    s  += __shfl_xor(s, d, 64);
    s2 += __shfl_xor(s2, d, 64);
  }
  float mu = s * (1.0f / 768.0f);
  float var = s2 * (1.0f / 768.0f) - mu * mu;
  float rs = rsqrtf(var + 1e-5f);
  uint2* outv = (uint2*)(xn + (long)row * 768);
  const float4* gv = (const float4*)g;
  const float4* bv2 = (const float4*)bb;
  #pragma unroll
  for (int i = 0; i < 3; ++i) {
    int c4 = lane + 64 * i;
    float4 gg = gv[c4], b4 = bv2[c4];
    union { bf16_t q[4]; uint2 u; } pk;
    pk.q[0] = (bf16_t)((v[i].x - mu) * rs * gg.x + b4.x);
    pk.q[1] = (bf16_t)((v[i].y - mu) * rs * gg.y + b4.y);
    pk.q[2] = (bf16_t)((v[i].z - mu) * rs * gg.z + b4.z);
    pk.q[3] = (bf16_t)((v[i].w - mu) * rs * gg.w + b4.w);
    outv[c4] = pk.u;
  }
}

// ---------------------------------------------------------------------------
// tanh-form GELU (max |err| ~3e-4 vs exact erf form; negligible after W2)
// ---------------------------------------------------------------------------
__device__ __forceinline__ float gelu_fast(float x) {
  float y = 0.7978845608f * (x + 0.044715f * x * x * x);
  float e = __expf(2.0f * y);                 // tanh(y) = (e-1)/(e+1)
  float t = 1.0f - 2.0f / (e + 1.0f);
  return 0.5f * x * (1.0f + t);
}

// ---------------------------------------------------------------------------
// Main GEMM: C[M,N] = A[M,K] * Bt[N,K]^T.  128x128 tile, BK=32, 4 waves.
// Compile-time KTOT/KS; __launch_bounds__(256,4) targets 128 unified regs
// (64 AGPR acc + <=64 VGPR) -> 4 blocks/CU.
// 1-D grid, lin = (bn*KS + ks)*BMPAD + bm  -> same bm => same XCD (lin%8).
// EPI: 0 = bf16 store (QKV)
//      3 = gelu(acc+bias) -> bf16  (MLP1)
//      4 = f32 plain store, masked (head)
//      5 = bf16 partial store at bout + ks*PSTRIDE  (embed/Wo/MLP2)
// ---------------------------------------------------------------------------
template <int EPI, int KTOT, int KS>
__global__ __launch_bounds__(256, 4) void gemm_bt(
    const bf16_t* __restrict__ A, const bf16_t* __restrict__ Bt,
    int ldc, int Mstore, int Nstore,
    const float* __restrict__ bias,
    float* __restrict__ fout, bf16_t* __restrict__ bout)
{
  int lin = blockIdx.x;
  int bm = lin % BMPAD;
  if (bm * 128 >= Mstore) return;
  int rest = lin / BMPAD;
  int ks = rest % KS;
  int bn = rest / KS;
  constexpr int Ksl = KTOT / KS;
  int k0 = ks * Ksl;

  __shared__ __align__(16) bf16_t As[128 * 32];
  __shared__ __align__(16) bf16_t Bs[128 * 32];
  int tid = threadIdx.x;
  int wave = tid >> 6, lane = tid & 63, quad = lane >> 4, l16 = lane & 15;
  int wm = wave >> 1, wn = wave & 1;
  const bf16_t* Ab = A + (long)bm * 128 * KTOT;
  const bf16_t* Bb = Bt + (long)bn * 128 * KTOT;

  f32x4 zero = {0.f, 0.f, 0.f, 0.f};
  f32x4 acc[4][4];
  #pragma unroll
  for (int i = 0; i < 4; ++i)
    #pragma unroll
    for (int j = 0; j < 4; ++j) acc[i][j] = zero;

  int f0 = tid * 16;
  int row0 = f0 >> 6;
  int ke0 = (f0 & 63) >> 1;

  for (int kt = k0; kt < k0 + Ksl; kt += 32) {
    __syncthreads();
    g2lds16(Ab + (long)row0 * KTOT + kt + ke0,        (char*)As + f0);
    g2lds16(Ab + (long)(row0 + 64) * KTOT + kt + ke0, (char*)As + f0 + 4096);
    g2lds16(Bb + (long)row0 * KTOT + kt + ke0,        (char*)Bs + f0);
    g2lds16(Bb + (long)(row0 + 64) * KTOT + kt + ke0, (char*)Bs + f0 + 4096);
    __syncthreads();

    bf16x8 af[4], bfr[4];
    #pragma unroll
    for (int i = 0; i < 4; ++i)
      af[i] = *(const bf16x8*)(As + (wm * 64 + i * 16 + l16) * 32 + quad * 8);
    #pragma unroll
    for (int j = 0; j < 4; ++j)
      bfr[j] = *(const bf16x8*)(Bs + (wn * 64 + j * 16 + l16) * 32 + quad * 8);
    #pragma unroll
    for (int i = 0; i < 4; ++i)
      #pragma unroll
      for (int j = 0; j < 4; ++j)
        acc[i][j] = __builtin_amdgcn_mfma_f32_16x16x32_bf16(af[i], bfr[j], acc[i][j], 0, 0, 0);
  }

  int m0 = bm * 128 + wm * 64, n0 = bn * 128 + wn * 64;
  #pragma unroll
  for (int i = 0; i < 4; ++i)
    #pragma unroll
    for (int j = 0; j < 4; ++j)
      #pragma unroll
      for (int r = 0; r < 4; ++r) {
        int row = m0 + i * 16 + quad * 4 + r;
        int col = n0 + j * 16 + l16;
        if (row >= Mstore || col >= Nstore) continue;
        float v = acc[i][j][r];
        if (EPI == 0) {
          bout[(long)row * ldc + col] = (bf16_t)v;
        } else if (EPI == 3) {
          bout[(long)row * ldc + col] = (bf16_t)gelu_fast(v + bias[col]);
        } else if (EPI == 4) {
          fout[(long)row * ldc + col] = v;
        } else {  // EPI 5: bf16 partial
          bout[(long)ks * PSTRIDE + (long)row * ldc + col] = (bf16_t)v;
        }
      }
}

// ---------------------------------------------------------------------------
// V transpose: qkv v-part -> Vt[bh][64][224] bf16, cols s>=196 zero-filled.
// ---------------------------------------------------------------------------
__global__ __launch_bounds__(256) void vtrans(
    const bf16_t* __restrict__ qkv, bf16_t* __restrict__ Vt)
{
  int bh = blockIdx.z, b = bh / 12, h = bh % 12;
  __shared__ bf16_t t[32][33];
  int e0 = blockIdx.x * 32, s0 = blockIdx.y * 32;
  int tx = threadIdx.x, ty = threadIdx.y;
  #pragma unroll
  for (int i = ty; i < 32; i += 8) {
    int s = s0 + i;
    bf16_t v = (bf16_t)0.0f;
    if (s < 196) v = qkv[(long)(b * 196 + s) * 2304 + 1536 + h * 64 + e0 + tx];
    t[i][tx] = v;
  }
  __syncthreads();
  #pragma unroll
  for (int i = ty; i < 32; i += 8) {
    int e = e0 + i, s = s0 + tx;
    if (s < 224) Vt[(long)bh * 64 * 224 + (long)e * 224 + s] = t[tx][i];
  }
}

// ---------------------------------------------------------------------------
// Fused attention: scores (Q@K^T) -> softmax -> P in LDS -> P@V -> att.
// One wave per (mt, bh). P LDS rows padded to 232 elems.
// ---------------------------------------------------------------------------
__global__ __launch_bounds__(64) void attn_fused(
    const bf16_t* __restrict__ qkv, const bf16_t* __restrict__ Vt,
    bf16_t* __restrict__ att)
{
  __shared__ __align__(16) bf16_t Pl[16 * 232];
  int mt = blockIdx.x, bh = blockIdx.y;
  int b = bh / 12, h = bh % 12;
  int lane = threadIdx.x, quad = lane >> 4, l16 = lane & 15;

  // zero the pad region cols 208..223
  #pragma unroll
  for (int i = 0; i < 4; ++i) {
    int idx = lane + 64 * i;              // 0..255
    Pl[(idx >> 4) * 232 + 208 + (idx & 15)] = (bf16_t)0.0f;
  }

  f32x4 zero = {0.f, 0.f, 0.f, 0.f};
  f32x4 acc[13];
  #pragma unroll
  for (int nt = 0; nt < 13; ++nt) acc[nt] = zero;

  long qoff = (long)(b * 196 + mt * 16 + l16) * 2304 + h * 64;
  #pragma unroll
  for (int kk = 0; kk < 2; ++kk) {
    bf16x8 a = *(const bf16x8*)(qkv + qoff + kk * 32 + quad * 8);
    #pragma unroll
    for (int nt = 0; nt < 13; ++nt) {
      long koff = (long)(b * 196 + nt * 16 + l16) * 2304 + 768 + h * 64 + kk * 32 + quad * 8;
      bf16x8 bb = *(const bf16x8*)(qkv + koff);
      acc[nt] = __builtin_amdgcn_mfma_f32_16x16x32_bf16(a, bb, acc[nt], 0, 0, 0);
    }
  }

  float p[13][4];
  #pragma unroll
  for (int nt = 0; nt < 13; ++nt)
    #pragma unroll
    for (int r = 0; r < 4; ++r) {
      float v = acc[nt][r] * 0.125f;
      if (nt == 12 && l16 >= 4) v = -1e30f;
      p[nt][r] = v;
    }

  #pragma unroll
  for (int r = 0; r < 4; ++r) {
    float mx = -1e30f;
    #pragma unroll
    for (int nt = 0; nt < 13; ++nt) mx = fmaxf(mx, p[nt][r]);
    #pragma unroll
    for (int d = 1; d < 16; d <<= 1) mx = fmaxf(mx, __shfl_xor(mx, d, 64));
    float sm = 0.f;
    #pragma unroll
    for (int nt = 0; nt < 13; ++nt) {
      float e = __expf(p[nt][r] - mx);
      p[nt][r] = e;
      sm += e;
    }
    #pragma unroll
    for (int d = 1; d < 16; d <<= 1) sm += __shfl_xor(sm, d, 64);
    float inv = 1.0f / sm;
    #pragma unroll
    for (int nt = 0; nt < 13; ++nt) p[nt][r] *= inv;
  }

  #pragma unroll
  for (int nt = 0; nt < 13; ++nt)
    #pragma unroll
    for (int r = 0; r < 4; ++r)
      Pl[(quad * 4 + r) * 232 + nt * 16 + l16] = (bf16_t)p[nt][r];
  __syncthreads();

  f32x4 pv[4];
  #pragma unroll
  for (int nt = 0; nt < 4; ++nt) pv[nt] = zero;
  const bf16_t* Vb = Vt + (long)bh * 64 * 224;
  #pragma unroll
  for (int ks = 0; ks < 7; ++ks) {
    bf16x8 a = *(const bf16x8*)(Pl + l16 * 232 + ks * 32 + quad * 8);
    #pragma unroll
    for (int nt = 0; nt < 4; ++nt) {
      bf16x8 bb = *(const bf16x8*)(Vb + (long)(nt * 16 + l16) * 224 + ks * 32 + quad * 8);
      pv[nt] = __builtin_amdgcn_mfma_f32_16x16x32_bf16(a, bb, pv[nt], 0, 0, 0);
    }
  }

  #pragma unroll
  for (int nt = 0; nt < 4; ++nt)
    #pragma unroll
    for (int r = 0; r < 4; ++r) {
      int t = mt * 16 + quad * 4 + r;
      if (t < 196)
        att[(long)(b * 196 + t) * 768 + h * 64 + nt * 16 + l16] = (bf16_t)pv[nt][r];
    }
}

// ---------------------------------------------------------------------------
// Mean pool + final MLP2 partial reduction (4 partials) + bias
// ---------------------------------------------------------------------------
__global__ __launch_bounds__(256) void meanpool_fuse(
    const float* __restrict__ h, const bf16_t* __restrict__ pbuf,
    const float* __restrict__ bias, bf16_t* __restrict__ hm)
{
  int d = blockIdx.y * 256 + threadIdx.x;
  int b = blockIdx.x;
  float s = 0.f;
  for (int t = 0; t < 196; ++t) {
    long idx = (long)(b * 196 + t) * 768 + d;
    float v = h[idx];
    #pragma unroll
    for (int pp = 0; pp < 4; ++pp) v += (float)pbuf[idx + pp * PSTRIDE];
    s += v;
  }
  hm[b * 768 + d] = (bf16_t)(s * (1.0f / 196.0f) + bias[d]);
}

// ---------------------------------------------------------------------------
// Host launch
// ---------------------------------------------------------------------------
extern "C" void kernel_launch(void* const* d_in, const int* in_sizes, int n_in,
                              void* d_out, int out_size, void* d_ws, size_t ws_size,
                              hipStream_t stream)
{
  const float* x       = (const float*)d_in[0];
  const float* embed_W = (const float*)d_in[1];
  const float* embed_b = (const float*)d_in[2];
  const float* Wq      = (const float*)d_in[3];
  const float* Wk      = (const float*)d_in[4];
  const float* Wv      = (const float*)d_in[5];
  const float* Wo      = (const float*)d_in[6];
  const float* bo      = (const float*)d_in[7];
  const float* ln1_g   = (const float*)d_in[8];
  const float* ln1_b   = (const float*)d_in[9];
  const float* ln2_g   = (const float*)d_in[10];
  const float* ln2_b   = (const float*)d_in[11];
  const float* W1      = (const float*)d_in[12];
  const float* b1      = (const float*)d_in[13];
  const float* W2      = (const float*)d_in[14];
  const float* b2      = (const float*)d_in[15];
  const float* head_W  = (const float*)d_in[16];

  char* p = (char*)d_ws;
  auto carve = [&](size_t bytes) {
    char* r = p;
    p += (bytes + 255) & ~(size_t)255;
    return r;
  };
  bf16_t* embed_Wt = (bf16_t*)carve(589824ull * 2);
  bf16_t* qkvT     = (bf16_t*)carve(21233664ull * 2);
  bf16_t* WoT      = (bf16_t*)carve(7077888ull * 2);
  bf16_t* W1T      = (bf16_t*)carve(28311552ull * 2);
  bf16_t* W2T      = (bf16_t*)carve(28311552ull * 2);
  bf16_t* headWt   = (bf16_t*)carve(786432ull * 2);
  bf16_t* patches  = (bf16_t*)carve(4816896ull * 2);
  float*  h        = (float*)carve(4816896ull * 4);
  bf16_t* xn       = (bf16_t*)carve(4816896ull * 2);
  bf16_t* qkv      = (bf16_t*)carve(14487552ull * 2);
  bf16_t* Vt       = (bf16_t*)carve(5505024ull * 2);
  bf16_t* hmlp     = (bf16_t*)carve(19267584ull * 2);
  bf16_t* att      = (bf16_t*)carve(4816896ull * 2);
  bf16_t* pbuf     = (bf16_t*)carve(4ull * PSTRIDE * 2);   // 4 partial bufs
  bf16_t* hm       = (bf16_t*)carve(98304ull * 2);
  (void)ws_size; (void)n_in; (void)in_sizes; (void)out_size;

  dim3 tb32(32, 8);

  // ---- weight prep ----
  tcvt<<<dim3(24, 24, 1),   tb32, 0, stream>>>(embed_W, embed_Wt, 768, 768, 0, 0, 0, 1);
  tcvt<<<dim3(24, 24, 12),  tb32, 0, stream>>>(Wo, WoT, 768, 768, 589824, 589824, 0, 1);
  tcvt<<<dim3(2, 24, 144),  tb32, 0, stream>>>(Wq, qkvT,           768, 64, 49152, 1769472, 49152, 12);
  tcvt<<<dim3(2, 24, 144),  tb32, 0, stream>>>(Wk, qkvT + 589824,  768, 64, 49152, 1769472, 49152, 12);
  tcvt<<<dim3(2, 24, 144),  tb32, 0, stream>>>(Wv, qkvT + 1179648, 768, 64, 49152, 1769472, 49152, 12);
  tcvt<<<dim3(96, 24, 12),  tb32, 0, stream>>>(W1, W1T, 768, 3072, 2359296, 2359296, 0, 1);
  tcvt<<<dim3(24, 96, 12),  tb32, 0, stream>>>(W2, W2T, 3072, 768, 2359296, 2359296, 0, 1);
  tcvt<<<dim3(32, 24, 1),   tb32, 0, stream>>>(head_W, headWt, 768, 1000, 0, 0, 0, 1);

  patchify<<<18816, 256, 0, stream>>>(x, patches);
  hinit<<<588, 256, 0, stream>>>(embed_b, h);

  // embed partials (split-K=2)
  gemm_bt<5, 768, 2><<<BMPAD * 6 * 2, 256, 0, stream>>>(
      patches, embed_Wt, 768, 6272, 768, nullptr, nullptr, pbuf);

  for (int l = 0; l < NLAYER; ++l) {
    // h += partials (+ bias of producer); xn = LN1(h)
    ln_fuse<<<1568, 256, 0, stream>>>(
        h, pbuf, l == 0 ? 2 : 4, l == 0 ? nullptr : b2 + (l - 1) * 768,
        ln1_g + l * 768, ln1_b + l * 768, xn);
    gemm_bt<0, 768, 1><<<BMPAD * 18, 256, 0, stream>>>(
        xn, qkvT + (long)l * 1769472, 2304, 6272, 2304,
        nullptr, nullptr, qkv);
    vtrans<<<dim3(2, 7, 384), tb32, 0, stream>>>(qkv, Vt);
    attn_fused<<<dim3(13, 384), 64, 0, stream>>>(qkv, Vt, att);
    gemm_bt<5, 768, 2><<<BMPAD * 6 * 2, 256, 0, stream>>>(
        att, WoT + (long)l * 589824, 768, 6272, 768,
        nullptr, nullptr, pbuf);
    ln_fuse<<<1568, 256, 0, stream>>>(
        h, pbuf, 2, bo + l * 768, ln2_g + l * 768, ln2_b + l * 768, xn);
    gemm_bt<3, 768, 1><<<BMPAD * 24, 256, 0, stream>>>(
        xn, W1T + (long)l * 2359296, 3072, 6272, 3072,
        b1 + l * 3072, nullptr, hmlp);
    gemm_bt<5, 3072, 4><<<BMPAD * 6 * 4, 256, 0, stream>>>(
        hmlp, W2T + (long)l * 2359296, 768, 6272, 768,
        nullptr, nullptr, pbuf);
  }

  meanpool_fuse<<<dim3(32, 3), 256, 0, stream>>>(h, pbuf, b2 + 11 * 768, hm);
  gemm_bt<4, 768, 1><<<BMPAD * 8, 256, 0, stream>>>(
      hm, headWt, 1000, 32, 1000, nullptr, (float*)d_out, nullptr);
}

// Round 5
// 3291.866 us; speedup vs baseline: 1.6050x; 1.0801x over previous
//
#include <hip/hip_runtime.h>
#include <cstdint>

// ---------------------------------------------------------------------------
// SimpleViT forward on gfx950. bf16 MFMA GEMMs, f32 residual stream.
// R5: BK=64 K-loop (half the barrier drains, 32 MFMA per stage) with
//     XOR-swizzled global->LDS staging (bank-conflict-free ds_read_b128:
//     physical granule p of row r holds logical granule p^(r&7)).
//     Split-K partials, XCD swizzle, fast GELU, launch_bounds(256,4) kept.
// ---------------------------------------------------------------------------

typedef __bf16 bf16_t;
typedef __bf16 bf16x8 __attribute__((ext_vector_type(8)));
typedef __bf16 bf16x4 __attribute__((ext_vector_type(4)));
typedef float  f32x4  __attribute__((ext_vector_type(4)));

#define NLAYER 12
#define BMPAD 56           // M-tiles padded to mult of 8 -> XCD co-location
#define PSTRIDE 4816896l   // elements per partial buffer [6272][768]

__device__ __forceinline__ void g2lds16(const void* g, void* l) {
  __builtin_amdgcn_global_load_lds(
      (const __attribute__((address_space(1))) void*)g,
      (__attribute__((address_space(3))) void*)l, 16, 0, 0);
}

// ---------------------------------------------------------------------------
// Weight transpose + f32->bf16: in [R][C] f32 -> out [C][R] bf16 (batched).
// ---------------------------------------------------------------------------
__global__ __launch_bounds__(256) void tcvt(
    const float* __restrict__ in, bf16_t* __restrict__ out,
    int R, int C, long inStride, long outOuter, long outInner, int innerN)
{
  int bi = blockIdx.z;
  in  += (long)bi * inStride;
  out += (long)(bi / innerN) * outOuter + (long)(bi % innerN) * outInner;
  __shared__ float t[32][33];
  int c0 = blockIdx.x * 32, r0 = blockIdx.y * 32;
  int tx = threadIdx.x, ty = threadIdx.y;
  #pragma unroll
  for (int i = ty; i < 32; i += 8) {
    int r = r0 + i, c = c0 + tx;
    if (r < R && c < C) t[i][tx] = in[(long)r * C + c];
  }
  __syncthreads();
  #pragma unroll
  for (int i = ty; i < 32; i += 8) {
    int c = c0 + i, r = r0 + tx;
    if (r < R && c < C) out[(long)c * R + r] = (bf16_t)t[tx][i];
  }
}

// ---------------------------------------------------------------------------
// Patchify: x[32,3,224,224] f32 -> patches[6272,768] bf16
// ---------------------------------------------------------------------------
__global__ __launch_bounds__(256) void patchify(
    const float* __restrict__ x, bf16_t* __restrict__ patches)
{
  int idx = blockIdx.x * 256 + threadIdx.x;
  int bt = idx / 768, pd = idx % 768;
  int b = bt / 196, t = bt % 196;
  int gh = t / 14, gw = t % 14;
  int p1 = pd / 48, rem = pd % 48;
  int p2 = rem / 3, c = rem % 3;
  float v = x[(((long)(b * 3 + c) * 224) + gh * 16 + p1) * 224 + gw * 16 + p2];
  patches[idx] = (bf16_t)v;
}

// ---------------------------------------------------------------------------
// h init: h[b][t][d] = posemb(t,d) + embed_b[d]
// ---------------------------------------------------------------------------
__global__ __launch_bounds__(256) void hinit(
    const float* __restrict__ eb, float* __restrict__ h)
{
  int idx = blockIdx.x * 256 + threadIdx.x;      // 0 .. 196*768-1
  int t = idx / 768, d = idx % 768;
  int gh = t / 14, gw = t % 14;
  int quadrant = d / 192, i = d % 192;
  float omega = powf(10000.0f, -(float)i / 191.0f);
  float arg = (quadrant < 2 ? (float)gw : (float)gh) * omega;
  float pv = ((quadrant & 1) == 0) ? sinf(arg) : cosf(arg);
  float v = pv + eb[d];
  #pragma unroll
  for (int b = 0; b < 32; ++b) h[(long)b * 150528 + idx] = v;
}

// ---------------------------------------------------------------------------
// Fused residual + LayerNorm: h += sum(partials) + bias; xn = LN(h)*g+b.
// ---------------------------------------------------------------------------
__global__ __launch_bounds__(256) void ln_fuse(
    float* __restrict__ h, const bf16_t* __restrict__ pbuf, int nparts,
    const float* __restrict__ bias, const float* __restrict__ g,
    const float* __restrict__ bb, bf16_t* __restrict__ xn)
{
  int row = blockIdx.x * 4 + (threadIdx.x >> 6);
  int lane = threadIdx.x & 63;
  float* hr = h + (long)row * 768;
  const bf16_t* pr = pbuf + (long)row * 768;
  float4 v[3];
  float s = 0.f, s2 = 0.f;
  #pragma unroll
  for (int i = 0; i < 3; ++i) {
    int c4 = lane + 64 * i;
    float4 hv = ((const float4*)hr)[c4];
    float4 acc = {0.f, 0.f, 0.f, 0.f};
    for (int pp = 0; pp < nparts; ++pp) {
      bf16x4 q = *(const bf16x4*)(pr + (long)pp * PSTRIDE + c4 * 4);
      acc.x += (float)q[0]; acc.y += (float)q[1];
      acc.z += (float)q[2]; acc.w += (float)q[3];
    }
    if (bias) {
      float4 bv = ((const float4*)bias)[c4];
      acc.x += bv.x; acc.y += bv.y; acc.z += bv.z; acc.w += bv.w;
    }
    hv.x += acc.x; hv.y += acc.y; hv.z += acc.z; hv.w += acc.w;
    ((float4*)hr)[c4] = hv;
    v[i] = hv;
    s  += hv.x + hv.y + hv.z + hv.w;
    s2 += hv.x * hv.x + hv.y * hv.y + hv.z * hv.z + hv.w * hv.w;
  }
  #pragma unroll
  for (int d = 1; d < 64; d <<= 1) {
    s  += __shfl_xor(s, d, 64);
    s2 += __shfl_xor(s2, d, 64);
  }
  float mu = s * (1.0f / 768.0f);
  float var = s2 * (1.0f / 768.0f) - mu * mu;
  float rs = rsqrtf(var + 1e-5f);
  uint2* outv = (uint2*)(xn + (long)row * 768);
  const float4* gv = (const float4*)g;
  const float4* bv2 = (const float4*)bb;
  #pragma unroll
  for (int i = 0; i < 3; ++i) {
    int c4 = lane + 64 * i;
    float4 gg = gv[c4], b4 = bv2[c4];
    union { bf16_t q[4]; uint2 u; } pk;
    pk.q[0] = (bf16_t)((v[i].x - mu) * rs * gg.x + b4.x);
    pk.q[1] = (bf16_t)((v[i].y - mu) * rs * gg.y + b4.y);
    pk.q[2] = (bf16_t)((v[i].z - mu) * rs * gg.z + b4.z);
    pk.q[3] = (bf16_t)((v[i].w - mu) * rs * gg.w + b4.w);
    outv[c4] = pk.u;
  }
}

// ---------------------------------------------------------------------------
// tanh-form GELU
// ---------------------------------------------------------------------------
__device__ __forceinline__ float gelu_fast(float x) {
  float y = 0.7978845608f * (x + 0.044715f * x * x * x);
  float e = __expf(2.0f * y);
  float t = 1.0f - 2.0f / (e + 1.0f);
  return 0.5f * x * (1.0f + t);
}

// ---------------------------------------------------------------------------
// Main GEMM: C[M,N] = A[M,K] * Bt[N,K]^T.  128x128 tile, BK=64, 4 waves.
// LDS rows are 64 elems (128B); granule (16B) p of row r holds logical
// granule p^(r&7)  -> ds_read_b128 spreads l16 lanes across all banks.
// 1-D grid, lin = (bn*KS + ks)*BMPAD + bm  -> same bm => same XCD (lin%8).
// EPI: 0 = bf16 store (QKV); 3 = gelu->bf16 (MLP1); 4 = f32 masked (head);
//      5 = bf16 partial at bout + ks*PSTRIDE (embed/Wo/MLP2)
// ---------------------------------------------------------------------------
template <int EPI, int KTOT, int KS>
__global__ __launch_bounds__(256, 4) void gemm_bt(
    const bf16_t* __restrict__ A, const bf16_t* __restrict__ Bt,
    int ldc, int Mstore, int Nstore,
    const float* __restrict__ bias,
    float* __restrict__ fout, bf16_t* __restrict__ bout)
{
  int lin = blockIdx.x;
  int bm = lin % BMPAD;
  if (bm * 128 >= Mstore) return;
  int rest = lin / BMPAD;
  int ks = rest % KS;
  int bn = rest / KS;
  constexpr int Ksl = KTOT / KS;
  int k0 = ks * Ksl;

  __shared__ __align__(16) bf16_t As[128 * 64];
  __shared__ __align__(16) bf16_t Bs[128 * 64];
  int tid = threadIdx.x;
  int wave = tid >> 6, lane = tid & 63, quad = lane >> 4, l16 = lane & 15;
  int wm = wave >> 1, wn = wave & 1;
  const bf16_t* Ab = A + (long)bm * 128 * KTOT;
  const bf16_t* Bb = Bt + (long)bn * 128 * KTOT;

  f32x4 zero = {0.f, 0.f, 0.f, 0.f};
  f32x4 acc[4][4];
  #pragma unroll
  for (int i = 0; i < 4; ++i)
    #pragma unroll
    for (int j = 0; j < 4; ++j) acc[i][j] = zero;

  // staging map: call c covers rows c*32 + tid/8; thread writes physical
  // granule tid%8 of its row; source logical granule = (tid%8) ^ (row&7).
  int srow = tid >> 3;                    // 0..31
  int sgcol = ((tid & 7) ^ (srow & 7)) * 8;  // source col (elems)
  int ldst = tid * 16;                    // LDS byte offset within 4KB call

  // fragment LDS offsets (elems), loop-invariant
  int aoff[2][4], boff[2][4];
  #pragma unroll
  for (int kh = 0; kh < 2; ++kh)
    #pragma unroll
    for (int i = 0; i < 4; ++i) {
      int ra = wm * 64 + i * 16 + l16;
      int rb = wn * 64 + i * 16 + l16;
      int pa = ((kh * 4 + quad) ^ (ra & 7)) * 8;
      int pb = ((kh * 4 + quad) ^ (rb & 7)) * 8;
      aoff[kh][i] = ra * 64 + pa;
      boff[kh][i] = rb * 64 + pb;
    }

  for (int kt = k0; kt < k0 + Ksl; kt += 64) {
    __syncthreads();
    #pragma unroll
    for (int c = 0; c < 4; ++c) {
      g2lds16(Ab + (long)(c * 32 + srow) * KTOT + kt + sgcol,
              (char*)As + c * 4096 + ldst);
      g2lds16(Bb + (long)(c * 32 + srow) * KTOT + kt + sgcol,
              (char*)Bs + c * 4096 + ldst);
    }
    __syncthreads();

    #pragma unroll
    for (int kh = 0; kh < 2; ++kh) {
      bf16x8 af[4], bfr[4];
      #pragma unroll
      for (int i = 0; i < 4; ++i) af[i] = *(const bf16x8*)(As + aoff[kh][i]);
      #pragma unroll
      for (int j = 0; j < 4; ++j) bfr[j] = *(const bf16x8*)(Bs + boff[kh][j]);
      #pragma unroll
      for (int i = 0; i < 4; ++i)
        #pragma unroll
        for (int j = 0; j < 4; ++j)
          acc[i][j] = __builtin_amdgcn_mfma_f32_16x16x32_bf16(af[i], bfr[j], acc[i][j], 0, 0, 0);
    }
  }

  int m0 = bm * 128 + wm * 64, n0 = bn * 128 + wn * 64;
  #pragma unroll
  for (int i = 0; i < 4; ++i)
    #pragma unroll
    for (int j = 0; j < 4; ++j)
      #pragma unroll
      for (int r = 0; r < 4; ++r) {
        int row = m0 + i * 16 + quad * 4 + r;
        int col = n0 + j * 16 + l16;
        if (row >= Mstore || col >= Nstore) continue;
        float v = acc[i][j][r];
        if (EPI == 0) {
          bout[(long)row * ldc + col] = (bf16_t)v;
        } else if (EPI == 3) {
          bout[(long)row * ldc + col] = (bf16_t)gelu_fast(v + bias[col]);
        } else if (EPI == 4) {
          fout[(long)row * ldc + col] = v;
        } else {  // EPI 5
          bout[(long)ks * PSTRIDE + (long)row * ldc + col] = (bf16_t)v;
        }
      }
}

// ---------------------------------------------------------------------------
// V transpose: qkv v-part -> Vt[bh][64][224] bf16, cols s>=196 zero-filled.
// ---------------------------------------------------------------------------
__global__ __launch_bounds__(256) void vtrans(
    const bf16_t* __restrict__ qkv, bf16_t* __restrict__ Vt)
{
  int bh = blockIdx.z, b = bh / 12, h = bh % 12;
  __shared__ bf16_t t[32][33];
  int e0 = blockIdx.x * 32, s0 = blockIdx.y * 32;
  int tx = threadIdx.x, ty = threadIdx.y;
  #pragma unroll
  for (int i = ty; i < 32; i += 8) {
    int s = s0 + i;
    bf16_t v = (bf16_t)0.0f;
    if (s < 196) v = qkv[(long)(b * 196 + s) * 2304 + 1536 + h * 64 + e0 + tx];
    t[i][tx] = v;
  }
  __syncthreads();
  #pragma unroll
  for (int i = ty; i < 32; i += 8) {
    int e = e0 + i, s = s0 + tx;
    if (s < 224) Vt[(long)bh * 64 * 224 + (long)e * 224 + s] = t[tx][i];
  }
}

// ---------------------------------------------------------------------------
// Fused attention: scores -> softmax -> P in LDS -> P@V -> att.
// ---------------------------------------------------------------------------
__global__ __launch_bounds__(64) void attn_fused(
    const bf16_t* __restrict__ qkv, const bf16_t* __restrict__ Vt,
    bf16_t* __restrict__ att)
{
  __shared__ __align__(16) bf16_t Pl[16 * 232];
  int mt = blockIdx.x, bh = blockIdx.y;
  int b = bh / 12, h = bh % 12;
  int lane = threadIdx.x, quad = lane >> 4, l16 = lane & 15;

  #pragma unroll
  for (int i = 0; i < 4; ++i) {
    int idx = lane + 64 * i;
    Pl[(idx >> 4) * 232 + 208 + (idx & 15)] = (bf16_t)0.0f;
  }

  f32x4 zero = {0.f, 0.f, 0.f, 0.f};
  f32x4 acc[13];
  #pragma unroll
  for (int nt = 0; nt < 13; ++nt) acc[nt] = zero;

  long qoff = (long)(b * 196 + mt * 16 + l16) * 2304 + h * 64;
  #pragma unroll
  for (int kk = 0; kk < 2; ++kk) {
    bf16x8 a = *(const bf16x8*)(qkv + qoff + kk * 32 + quad * 8);
    #pragma unroll
    for (int nt = 0; nt < 13; ++nt) {
      long koff = (long)(b * 196 + nt * 16 + l16) * 2304 + 768 + h * 64 + kk * 32 + quad * 8;
      bf16x8 bb = *(const bf16x8*)(qkv + koff);
      acc[nt] = __builtin_amdgcn_mfma_f32_16x16x32_bf16(a, bb, acc[nt], 0, 0, 0);
    }
  }

  float p[13][4];
  #pragma unroll
  for (int nt = 0; nt < 13; ++nt)
    #pragma unroll
    for (int r = 0; r < 4; ++r) {
      float v = acc[nt][r] * 0.125f;
      if (nt == 12 && l16 >= 4) v = -1e30f;
      p[nt][r] = v;
    }

  #pragma unroll
  for (int r = 0; r < 4; ++r) {
    float mx = -1e30f;
    #pragma unroll
    for (int nt = 0; nt < 13; ++nt) mx = fmaxf(mx, p[nt][r]);
    #pragma unroll
    for (int d = 1; d < 16; d <<= 1) mx = fmaxf(mx, __shfl_xor(mx, d, 64));
    float sm = 0.f;
    #pragma unroll
    for (int nt = 0; nt < 13; ++nt) {
      float e = __expf(p[nt][r] - mx);
      p[nt][r] = e;
      sm += e;
    }
    #pragma unroll
    for (int d = 1; d < 16; d <<= 1) sm += __shfl_xor(sm, d, 64);
    float inv = 1.0f / sm;
    #pragma unroll
    for (int nt = 0; nt < 13; ++nt) p[nt][r] *= inv;
  }

  #pragma unroll
  for (int nt = 0; nt < 13; ++nt)
    #pragma unroll
    for (int r = 0; r < 4; ++r)
      Pl[(quad * 4 + r) * 232 + nt * 16 + l16] = (bf16_t)p[nt][r];
  __syncthreads();

  f32x4 pv[4];
  #pragma unroll
  for (int nt = 0; nt < 4; ++nt) pv[nt] = zero;
  const bf16_t* Vb = Vt + (long)bh * 64 * 224;
  #pragma unroll
  for (int ks = 0; ks < 7; ++ks) {
    bf16x8 a = *(const bf16x8*)(Pl + l16 * 232 + ks * 32 + quad * 8);
    #pragma unroll
    for (int nt = 0; nt < 4; ++nt) {
      bf16x8 bb = *(const bf16x8*)(Vb + (long)(nt * 16 + l16) * 224 + ks * 32 + quad * 8);
      pv[nt] = __builtin_amdgcn_mfma_f32_16x16x32_bf16(a, bb, pv[nt], 0, 0, 0);
    }
  }

  #pragma unroll
  for (int nt = 0; nt < 4; ++nt)
    #pragma unroll
    for (int r = 0; r < 4; ++r) {
      int t = mt * 16 + quad * 4 + r;
      if (t < 196)
        att[(long)(b * 196 + t) * 768 + h * 64 + nt * 16 + l16] = (bf16_t)pv[nt][r];
    }
}

// ---------------------------------------------------------------------------
// Mean pool + final MLP2 partial reduction (4 partials) + bias
// ---------------------------------------------------------------------------
__global__ __launch_bounds__(256) void meanpool_fuse(
    const float* __restrict__ h, const bf16_t* __restrict__ pbuf,
    const float* __restrict__ bias, bf16_t* __restrict__ hm)
{
  int d = blockIdx.y * 256 + threadIdx.x;
  int b = blockIdx.x;
  float s = 0.f;
  for (int t = 0; t < 196; ++t) {
    long idx = (long)(b * 196 + t) * 768 + d;
    float v = h[idx];
    #pragma unroll
    for (int pp = 0; pp < 4; ++pp) v += (float)pbuf[idx + pp * PSTRIDE];
    s += v;
  }
  hm[b * 768 + d] = (bf16_t)(s * (1.0f / 196.0f) + bias[d]);
}

// ---------------------------------------------------------------------------
// Host launch
// ---------------------------------------------------------------------------
extern "C" void kernel_launch(void* const* d_in, const int* in_sizes, int n_in,
                              void* d_out, int out_size, void* d_ws, size_t ws_size,
                              hipStream_t stream)
{
  const float* x       = (const float*)d_in[0];
  const float* embed_W = (const float*)d_in[1];
  const float* embed_b = (const float*)d_in[2];
  const float* Wq      = (const float*)d_in[3];
  const float* Wk      = (const float*)d_in[4];
  const float* Wv      = (const float*)d_in[5];
  const float* Wo      = (const float*)d_in[6];
  const float* bo      = (const float*)d_in[7];
  const float* ln1_g   = (const float*)d_in[8];
  const float* ln1_b   = (const float*)d_in[9];
  const float* ln2_g   = (const float*)d_in[10];
  const float* ln2_b   = (const float*)d_in[11];
  const float* W1      = (const float*)d_in[12];
  const float* b1      = (const float*)d_in[13];
  const float* W2      = (const float*)d_in[14];
  const float* b2      = (const float*)d_in[15];
  const float* head_W  = (const float*)d_in[16];

  char* p = (char*)d_ws;
  auto carve = [&](size_t bytes) {
    char* r = p;
    p += (bytes + 255) & ~(size_t)255;
    return r;
  };
  bf16_t* embed_Wt = (bf16_t*)carve(589824ull * 2);
  bf16_t* qkvT     = (bf16_t*)carve(21233664ull * 2);
  bf16_t* WoT      = (bf16_t*)carve(7077888ull * 2);
  bf16_t* W1T      = (bf16_t*)carve(28311552ull * 2);
  bf16_t* W2T      = (bf16_t*)carve(28311552ull * 2);
  bf16_t* headWt   = (bf16_t*)carve(786432ull * 2);
  bf16_t* patches  = (bf16_t*)carve(4816896ull * 2);
  float*  h        = (float*)carve(4816896ull * 4);
  bf16_t* xn       = (bf16_t*)carve(4816896ull * 2);
  bf16_t* qkv      = (bf16_t*)carve(14487552ull * 2);
  bf16_t* Vt       = (bf16_t*)carve(5505024ull * 2);
  bf16_t* hmlp     = (bf16_t*)carve(19267584ull * 2);
  bf16_t* att      = (bf16_t*)carve(4816896ull * 2);
  bf16_t* pbuf     = (bf16_t*)carve(4ull * PSTRIDE * 2);
  bf16_t* hm       = (bf16_t*)carve(98304ull * 2);
  (void)ws_size; (void)n_in; (void)in_sizes; (void)out_size;

  dim3 tb32(32, 8);

  tcvt<<<dim3(24, 24, 1),   tb32, 0, stream>>>(embed_W, embed_Wt, 768, 768, 0, 0, 0, 1);
  tcvt<<<dim3(24, 24, 12),  tb32, 0, stream>>>(Wo, WoT, 768, 768, 589824, 589824, 0, 1);
  tcvt<<<dim3(2, 24, 144),  tb32, 0, stream>>>(Wq, qkvT,           768, 64, 49152, 1769472, 49152, 12);
  tcvt<<<dim3(2, 24, 144),  tb32, 0, stream>>>(Wk, qkvT + 589824,  768, 64, 49152, 1769472, 49152, 12);
  tcvt<<<dim3(2, 24, 144),  tb32, 0, stream>>>(Wv, qkvT + 1179648, 768, 64, 49152, 1769472, 49152, 12);
  tcvt<<<dim3(96, 24, 12),  tb32, 0, stream>>>(W1, W1T, 768, 3072, 2359296, 2359296, 0, 1);
  tcvt<<<dim3(24, 96, 12),  tb32, 0, stream>>>(W2, W2T, 3072, 768, 2359296, 2359296, 0, 1);
  tcvt<<<dim3(32, 24, 1),   tb32, 0, stream>>>(head_W, headWt, 768, 1000, 0, 0, 0, 1);

  patchify<<<18816, 256, 0, stream>>>(x, patches);
  hinit<<<588, 256, 0, stream>>>(embed_b, h);

  gemm_bt<5, 768, 2><<<BMPAD * 6 * 2, 256, 0, stream>>>(
      patches, embed_Wt, 768, 6272, 768, nullptr, nullptr, pbuf);

  for (int l = 0; l < NLAYER; ++l) {
    ln_fuse<<<1568, 256, 0, stream>>>(
        h, pbuf, l == 0 ? 2 : 4, l == 0 ? nullptr : b2 + (l - 1) * 768,
        ln1_g + l * 768, ln1_b + l * 768, xn);
    gemm_bt<0, 768, 1><<<BMPAD * 18, 256, 0, stream>>>(
        xn, qkvT + (long)l * 1769472, 2304, 6272, 2304,
        nullptr, nullptr, qkv);
    vtrans<<<dim3(2, 7, 384), tb32, 0, stream>>>(qkv, Vt);
    attn_fused<<<dim3(13, 384), 64, 0, stream>>>(qkv, Vt, att);
    gemm_bt<5, 768, 2><<<BMPAD * 6 * 2, 256, 0, stream>>>(
        att, WoT + (long)l * 589824, 768, 6272, 768,
        nullptr, nullptr, pbuf);
    ln_fuse<<<1568, 256, 0, stream>>>(
        h, pbuf, 2, bo + l * 768, ln2_g + l * 768, ln2_b + l * 768, xn);
    gemm_bt<3, 768, 1><<<BMPAD * 24, 256, 0, stream>>>(
        xn, W1T + (long)l * 2359296, 3072, 6272, 3072,
        b1 + l * 3072, nullptr, hmlp);
    gemm_bt<5, 3072, 4><<<BMPAD * 6 * 4, 256, 0, stream>>>(
        hmlp, W2T + (long)l * 2359296, 768, 6272, 768,
        nullptr, nullptr, pbuf);
  }

  meanpool_fuse<<<dim3(32, 3), 256, 0, stream>>>(h, pbuf, b2 + 11 * 768, hm);
  gemm_bt<4, 768, 1><<<BMPAD * 8, 256, 0, stream>>>(
      hm, headWt, 1000, 32, 1000, nullptr, (float*)d_out, nullptr);
}